// Round 1
// baseline (114.221 us; speedup 1.0000x reference)
//
#include <hip/hip_runtime.h>

// Problem constants (from reference): B=32, L1=L2=64, DIM_HID=256, FEAT=512
#define BB 32
#define LL 64
#define HH 256
#define FF 512
#define WSTRIDE 1024   // W is [256, 1024] row-major
#define MROWS 4096     // combined rows: 2048 (x1) + 2048 (x2)

// ---------------- Kernel 1: init output with padding term ----------------
// out[b,h] = (L*L - s1*s2) * relu(bias[h]) / (s1*s2)
__global__ void init_out_kernel(const int* __restrict__ s1,
                                const int* __restrict__ s2,
                                const float* __restrict__ bias,
                                float* __restrict__ out) {
    const int b = blockIdx.x;
    const int h = threadIdx.x;
    const float n1 = (float)s1[b];
    const float n2 = (float)s2[b];
    const float denom = n1 * n2;
    const float pad = (float)(LL * LL) - denom;
    const float rb = fmaxf(bias[h], 0.0f);
    out[b * HH + h] = pad * rb / denom;
}

// ---------------- Kernel 2: fp32 GEMM  y[row,h] = sum_k A[row,k]*W[h,woff+k] ----------------
// rows [0,2048)   : A = x1, woff = 0
// rows [2048,4096): A = x2, woff = 512, += bias  (fold bias into y2')
// Tile: 64 rows x 64 cols, K-tile 32. LDS stored k-major: As[kk][row].
__global__ __launch_bounds__(256, 2)
void gemm_kernel(const float* __restrict__ x1,
                 const float* __restrict__ x2,
                 const float* __restrict__ W,
                 const float* __restrict__ bias,
                 float* __restrict__ y) {
    const int colBase = blockIdx.x * 64;   // h tile
    const int rowBase = blockIdx.y * 64;   // combined row tile (never straddles 2048)
    const bool second = (rowBase >= 2048);
    const float* __restrict__ A = second ? x2 : x1;
    const int arow0 = second ? (rowBase - 2048) : rowBase;
    const int woff  = second ? FF : 0;

    __shared__ __align__(16) float As[32][68];  // stride 68 floats = 272B (16B aligned rows)
    __shared__ __align__(16) float Bs[32][68];

    const int t  = threadIdx.x;
    const int tx = t & 15;   // col group  -> cols tx*4 .. +3
    const int ty = t >> 4;   // row group  -> rows ty*4 .. +3

    const int srow = t >> 3;  // staging row 0..31 (plus +32 on 2nd half)
    const int skq  = t & 7;   // staging k-quad

    float acc[4][4] = {};

    for (int k0 = 0; k0 < FF; k0 += 32) {
        // stage A and B tiles, transposed to k-major
        #pragma unroll
        for (int half = 0; half < 2; ++half) {
            const int r = srow + half * 32;
            const float4 va = *(const float4*)&A[(size_t)(arow0 + r) * FF + (k0 + skq * 4)];
            As[skq * 4 + 0][r] = va.x;
            As[skq * 4 + 1][r] = va.y;
            As[skq * 4 + 2][r] = va.z;
            As[skq * 4 + 3][r] = va.w;
            const float4 vb = *(const float4*)&W[(size_t)(colBase + r) * WSTRIDE + (woff + k0 + skq * 4)];
            Bs[skq * 4 + 0][r] = vb.x;
            Bs[skq * 4 + 1][r] = vb.y;
            Bs[skq * 4 + 2][r] = vb.z;
            Bs[skq * 4 + 3][r] = vb.w;
        }
        __syncthreads();

        #pragma unroll
        for (int kk = 0; kk < 32; ++kk) {
            const float4 av = *(const float4*)&As[kk][ty * 4];
            const float4 bv = *(const float4*)&Bs[kk][tx * 4];
            const float a_[4] = {av.x, av.y, av.z, av.w};
            const float b_[4] = {bv.x, bv.y, bv.z, bv.w};
            #pragma unroll
            for (int r = 0; r < 4; ++r)
                #pragma unroll
                for (int c = 0; c < 4; ++c)
                    acc[r][c] = fmaf(a_[r], b_[c], acc[r][c]);
        }
        __syncthreads();
    }

    // epilogue: optional bias fold (for x2 half), coalesced float4 stores
    #pragma unroll
    for (int r = 0; r < 4; ++r) {
        const int row = rowBase + ty * 4 + r;
        const int col = colBase + tx * 4;
        float4 v = make_float4(acc[r][0], acc[r][1], acc[r][2], acc[r][3]);
        if (second) {
            v.x += bias[col + 0];
            v.y += bias[col + 1];
            v.z += bias[col + 2];
            v.w += bias[col + 3];
        }
        *(float4*)&y[(size_t)row * HH + col] = v;
    }
}

// ---------------- Kernel 3: masked pair relu-sum ----------------
// For each (b, i-chunk): thread h accumulates sum over i in chunk (i<s1), j<s2 of
// relu(y1[b,i,h] + y2'[b,j,h]); atomically adds partial/denom to out.
#define ICH 8
__global__ __launch_bounds__(256)
void pair_kernel(const float* __restrict__ y,
                 const int* __restrict__ s1p,
                 const int* __restrict__ s2p,
                 float* __restrict__ out) {
    const int b  = blockIdx.x;
    const int ic = blockIdx.y;
    const int h  = threadIdx.x;
    const int n1 = s1p[b];
    const int n2 = s2p[b];
    const int i0 = ic * ICH;
    if (i0 >= n1) return;

    const float* __restrict__ y1 = y + (size_t)(b * LL) * HH + h;
    const float* __restrict__ y2 = y + (size_t)(2048 + b * LL) * HH + h;

    float r1[ICH];
    #pragma unroll
    for (int ii = 0; ii < ICH; ++ii) {
        const int i = i0 + ii;
        // invalid i -> -1e30 so relu(r1 + v2) == 0 (no fast-math assumed)
        r1[ii] = (i < n1) ? y1[(size_t)i * HH] : -1e30f;
    }

    float acc = 0.0f;
    for (int j = 0; j < n2; ++j) {
        const float v2 = y2[(size_t)j * HH];
        #pragma unroll
        for (int ii = 0; ii < ICH; ++ii)
            acc += fmaxf(r1[ii] + v2, 0.0f);
    }

    const float denom = (float)(n1 * n2);
    atomicAdd(&out[b * HH + h], acc / denom);
}

extern "C" void kernel_launch(void* const* d_in, const int* in_sizes, int n_in,
                              void* d_out, int out_size, void* d_ws, size_t ws_size,
                              hipStream_t stream) {
    const float* x1 = (const float*)d_in[0];
    const int*   s1 = (const int*)d_in[1];
    const float* x2 = (const float*)d_in[2];
    const int*   s2 = (const int*)d_in[3];
    const float* W  = (const float*)d_in[4];
    const float* b  = (const float*)d_in[5];
    float* out = (float*)d_out;
    float* y   = (float*)d_ws;   // [4096, 256] fp32 = 4 MB: y1 rows 0..2047, y2' rows 2048..4095

    // 1) init output with padding term (also overwrites the 0xAA poison)
    init_out_kernel<<<BB, HH, 0, stream>>>(s1, s2, b, out);

    // 2) GEMM: 4096x256, K=512
    gemm_kernel<<<dim3(HH / 64, MROWS / 64), 256, 0, stream>>>(x1, x2, W, b, y);

    // 3) masked pair relu-sum with atomic accumulation
    pair_kernel<<<dim3(BB, LL / ICH), 256, 0, stream>>>(y, s1, s2, out);
}

// Round 2
// 85.677 us; speedup vs baseline: 1.3332x; 1.3332x over previous
//
#include <hip/hip_runtime.h>

// Problem constants: B=32, L1=L2=64, DIM_HID=256, FEAT=512
#define BB 32
#define LL 64
#define HH 256
#define FF 512
#define WSTRIDE 1024   // W is [256, 1024] row-major
#define MROWS 4096     // combined rows: 2048 (x1) + 2048 (x2)

typedef float float4v __attribute__((ext_vector_type(4)));
typedef short short8  __attribute__((ext_vector_type(8)));

// fp32 -> bf16 (RNE), bit-level
static __device__ __forceinline__ unsigned short f2bf(float x) {
    union { float f; unsigned int u; } v; v.f = x;
    v.u += 0x7FFFu + ((v.u >> 16) & 1u);
    return (unsigned short)(v.u >> 16);
}

// ---------------- Kernel 1: init output with padding term ----------------
// out[b,h] = (L*L - s1*s2) * relu(bias[h]) / (s1*s2)
__global__ void init_out_kernel(const int* __restrict__ s1,
                                const int* __restrict__ s2,
                                const float* __restrict__ bias,
                                float* __restrict__ out) {
    const int b = blockIdx.x;
    const int h = threadIdx.x;
    const float denom = (float)s1[b] * (float)s2[b];
    const float pad = (float)(LL * LL) - denom;
    out[b * HH + h] = pad * fmaxf(bias[h], 0.0f) / denom;
}

// ---------------- Kernel 2: bf16 MFMA GEMM ----------------
// y[row,h] = sum_k A[row,k] * W[h, woff+k]   (cast to bf16 on LDS staging)
// rows [0,2048): A=x1, woff=0; rows [2048,4096): A=x2, woff=512, +bias
// Tile BM=64 x BN=64, BK=64; 4 waves (2x2), each wave 32x32 via 2x2 MFMA tiles.
#define BK 64
#define LDS_STRIDE 72   // 64 + 8 bf16; 144 B rows = 9*16 B (b128-aligned, optimal bank spread)
__global__ __launch_bounds__(256)
void gemm_mfma_kernel(const float* __restrict__ x1,
                      const float* __restrict__ x2,
                      const float* __restrict__ W,
                      const float* __restrict__ bias,
                      float* __restrict__ y) {
    const int colBase = blockIdx.x * 64;   // h tile (N)
    const int rowBase = blockIdx.y * 64;   // combined row tile (M); never straddles 2048
    const bool second = (rowBase >= 2048);
    const float* __restrict__ A = second ? x2 : x1;
    const int arow0 = second ? (rowBase - 2048) : rowBase;
    const int woff  = second ? FF : 0;

    __shared__ __align__(16) unsigned short As[64][LDS_STRIDE];  // As[r][k] k-contiguous
    __shared__ __align__(16) unsigned short Bs[64][LDS_STRIDE];  // Bs[h][k] k-contiguous

    const int t    = threadIdx.x;
    const int lane = t & 63;
    const int wid  = t >> 6;           // 0..3
    const int wm   = wid >> 1;         // wave row 0..1  -> rows wm*32..+31
    const int wn   = wid & 1;          // wave col 0..1  -> cols wn*32..+31
    const int lm   = lane & 15;
    const int quad = lane >> 4;        // 0..3

    // staging mapping: thread -> (row r, k-quarter kq), loads 16 fp32 (64 B)
    const int r  = t >> 2;             // 0..63
    const int kq = t & 3;              // k offset kq*16

    const float* aPtr = A + (size_t)(arow0 + r) * FF + kq * 16;
    const float* bPtr = W + (size_t)(colBase + r) * WSTRIDE + woff + kq * 16;

    float4v acc[2][2];
    #pragma unroll
    for (int i = 0; i < 2; ++i)
        #pragma unroll
        for (int j = 0; j < 2; ++j)
            acc[i][j] = (float4v){0.f, 0.f, 0.f, 0.f};

    // register prefetch of tile 0
    float4 pa[4], pb[4];
    #pragma unroll
    for (int q = 0; q < 4; ++q) {
        pa[q] = *(const float4*)(aPtr + q * 4);
        pb[q] = *(const float4*)(bPtr + q * 4);
    }

    const unsigned short* aB0 = &As[wm * 32 + lm][quad * 8];
    const unsigned short* aB1 = &As[wm * 32 + 16 + lm][quad * 8];
    const unsigned short* bB0 = &Bs[wn * 32 + lm][quad * 8];
    const unsigned short* bB1 = &Bs[wn * 32 + 16 + lm][quad * 8];

    for (int kt = 0; kt < FF / BK; ++kt) {
        // convert prefetched regs -> bf16 -> LDS (2 b128 writes each for A and B)
        short8 wa0, wa1, wb0, wb1;
        {
            const float* fa = (const float*)pa;
            const float* fb = (const float*)pb;
            #pragma unroll
            for (int e = 0; e < 8; ++e) {
                ((unsigned short*)&wa0)[e] = f2bf(fa[e]);
                ((unsigned short*)&wa1)[e] = f2bf(fa[e + 8]);
                ((unsigned short*)&wb0)[e] = f2bf(fb[e]);
                ((unsigned short*)&wb1)[e] = f2bf(fb[e + 8]);
            }
        }
        *(short8*)&As[r][kq * 16]     = wa0;
        *(short8*)&As[r][kq * 16 + 8] = wa1;
        *(short8*)&Bs[r][kq * 16]     = wb0;
        *(short8*)&Bs[r][kq * 16 + 8] = wb1;
        __syncthreads();

        // prefetch next tile's globals (overlaps with frag reads + MFMA below)
        if (kt + 1 < FF / BK) {
            const float* aN = aPtr + (kt + 1) * BK;
            const float* bN = bPtr + (kt + 1) * BK;
            #pragma unroll
            for (int q = 0; q < 4; ++q) {
                pa[q] = *(const float4*)(aN + q * 4);
                pb[q] = *(const float4*)(bN + q * 4);
            }
        }

        // 2 K-steps of 32, 4 MFMA each
        #pragma unroll
        for (int ks = 0; ks < 2; ++ks) {
            const short8 a0 = *(const short8*)(aB0 + ks * 32);
            const short8 a1 = *(const short8*)(aB1 + ks * 32);
            const short8 b0 = *(const short8*)(bB0 + ks * 32);
            const short8 b1 = *(const short8*)(bB1 + ks * 32);
            acc[0][0] = __builtin_amdgcn_mfma_f32_16x16x32_bf16(a0, b0, acc[0][0], 0, 0, 0);
            acc[0][1] = __builtin_amdgcn_mfma_f32_16x16x32_bf16(a0, b1, acc[0][1], 0, 0, 0);
            acc[1][0] = __builtin_amdgcn_mfma_f32_16x16x32_bf16(a1, b0, acc[1][0], 0, 0, 0);
            acc[1][1] = __builtin_amdgcn_mfma_f32_16x16x32_bf16(a1, b1, acc[1][1], 0, 0, 0);
        }
        __syncthreads();
    }

    // epilogue: C/D layout col=lane&15, row=quad*4+reg (m89-verified)
    #pragma unroll
    for (int im = 0; im < 2; ++im) {
        #pragma unroll
        for (int in = 0; in < 2; ++in) {
            const int col = colBase + wn * 32 + in * 16 + lm;
            const float bv = second ? bias[col] : 0.0f;
            #pragma unroll
            for (int j = 0; j < 4; ++j) {
                const int row = rowBase + wm * 32 + im * 16 + quad * 4 + j;
                y[(size_t)row * HH + col] = acc[im][in][j] + bv;
            }
        }
    }
}

// ---------------- Kernel 3: masked pair relu-sum ----------------
// block (b, ic): 4 i-rows, thread h; 4 independent accumulators + j-unroll-4
// to break the serial add chain; atomicAdd partial/denom into out.
#define ICH 4
__global__ __launch_bounds__(256)
void pair_kernel(const float* __restrict__ y,
                 const int* __restrict__ s1p,
                 const int* __restrict__ s2p,
                 float* __restrict__ out) {
    const int b  = blockIdx.x;
    const int ic = blockIdx.y;
    const int h  = threadIdx.x;
    const int n1 = s1p[b];
    const int n2 = s2p[b];
    const int i0 = ic * ICH;
    if (i0 >= n1) return;

    const float* __restrict__ y1 = y + (size_t)(b * LL) * HH + h;
    const float* __restrict__ y2 = y + (size_t)(2048 + b * LL) * HH + h;

    float r1[ICH];
    #pragma unroll
    for (int ii = 0; ii < ICH; ++ii) {
        const int i = i0 + ii;
        r1[ii] = (i < n1) ? y1[(size_t)i * HH] : -1e30f;  // invalid -> relu gives 0
    }

    float a0 = 0.f, a1 = 0.f, a2 = 0.f, a3 = 0.f;
    int j = 0;
    for (; j + 4 <= n2; j += 4) {
        const float v0 = y2[(size_t)(j + 0) * HH];
        const float v1 = y2[(size_t)(j + 1) * HH];
        const float v2 = y2[(size_t)(j + 2) * HH];
        const float v3 = y2[(size_t)(j + 3) * HH];
        a0 += fmaxf(r1[0] + v0, 0.f); a1 += fmaxf(r1[1] + v0, 0.f);
        a2 += fmaxf(r1[2] + v0, 0.f); a3 += fmaxf(r1[3] + v0, 0.f);
        a0 += fmaxf(r1[0] + v1, 0.f); a1 += fmaxf(r1[1] + v1, 0.f);
        a2 += fmaxf(r1[2] + v1, 0.f); a3 += fmaxf(r1[3] + v1, 0.f);
        a0 += fmaxf(r1[0] + v2, 0.f); a1 += fmaxf(r1[1] + v2, 0.f);
        a2 += fmaxf(r1[2] + v2, 0.f); a3 += fmaxf(r1[3] + v2, 0.f);
        a0 += fmaxf(r1[0] + v3, 0.f); a1 += fmaxf(r1[1] + v3, 0.f);
        a2 += fmaxf(r1[2] + v3, 0.f); a3 += fmaxf(r1[3] + v3, 0.f);
    }
    for (; j < n2; ++j) {
        const float v = y2[(size_t)j * HH];
        a0 += fmaxf(r1[0] + v, 0.f); a1 += fmaxf(r1[1] + v, 0.f);
        a2 += fmaxf(r1[2] + v, 0.f); a3 += fmaxf(r1[3] + v, 0.f);
    }

    const float denom = (float)(n1 * n2);
    atomicAdd(&out[b * HH + h], (a0 + a1 + a2 + a3) / denom);
}

extern "C" void kernel_launch(void* const* d_in, const int* in_sizes, int n_in,
                              void* d_out, int out_size, void* d_ws, size_t ws_size,
                              hipStream_t stream) {
    const float* x1 = (const float*)d_in[0];
    const int*   s1 = (const int*)d_in[1];
    const float* x2 = (const float*)d_in[2];
    const int*   s2 = (const int*)d_in[3];
    const float* W  = (const float*)d_in[4];
    const float* b  = (const float*)d_in[5];
    float* out = (float*)d_out;
    float* y   = (float*)d_ws;   // [4096, 256] fp32 = 4 MB

    init_out_kernel<<<BB, HH, 0, stream>>>(s1, s2, b, out);
    gemm_mfma_kernel<<<dim3(HH / 64, MROWS / 64), 256, 0, stream>>>(x1, x2, W, b, y);
    pair_kernel<<<dim3(BB, LL / ICH), 256, 0, stream>>>(y, s1, s2, out);
}

// Round 3
// 78.425 us; speedup vs baseline: 1.4564x; 1.0925x over previous
//
#include <hip/hip_runtime.h>

// Problem constants: B=32, L1=L2=64, DIM_HID=256, FEAT=512
#define BB 32
#define LL 64
#define HH 256
#define FF 512
#define WSTRIDE 1024   // W is [256, 1024] row-major
#define HT 32          // h-tile per block
#define BK 64          // K-tile
#define LSTR 72        // bf16 LDS stride: 144 B rows = 9*16 B, conflict-free b128 spread
#define YSTR 33        // f32 y-tile stride (+1 pad)

typedef float float4v __attribute__((ext_vector_type(4)));
typedef short short8  __attribute__((ext_vector_type(8)));

// fp32 -> bf16 (RNE), bit-level (R2-verified)
static __device__ __forceinline__ unsigned short f2bf(float x) {
    union { float f; unsigned int u; } v; v.f = x;
    v.u += 0x7FFFu + ((v.u >> 16) & 1u);
    return (unsigned short)(v.u >> 16);
}

static __device__ __forceinline__ void cvt_store16(const float4* p, unsigned short* dst) {
    const float* f = (const float*)p;
    short8 lo, hi;
    #pragma unroll
    for (int e = 0; e < 8; ++e) {
        ((unsigned short*)&lo)[e] = f2bf(f[e]);
        ((unsigned short*)&hi)[e] = f2bf(f[e + 8]);
    }
    *(short8*)dst = lo;
    *(short8*)(dst + 8) = hi;
}

static __device__ __forceinline__ void cvt_store8(const float4* p, unsigned short* dst) {
    const float* f = (const float*)p;
    short8 lo;
    #pragma unroll
    for (int e = 0; e < 8; ++e)
        ((unsigned short*)&lo)[e] = f2bf(f[e]);
    *(short8*)dst = lo;
}

// One block per (batch b, h-tile of 32). Computes y1=x1[b]@W1^T (64x32) and
// y2'=x2[b]@W2^T+b (64x32) into LDS via bf16 MFMA, then the masked pair
// relu-sum + padding term, writing out[b, h0:h0+32] directly. No d_ws.
__global__ __launch_bounds__(256)
void fused_kernel(const float* __restrict__ x1,
                  const int* __restrict__ s1p,
                  const float* __restrict__ x2,
                  const int* __restrict__ s2p,
                  const float* __restrict__ W,
                  const float* __restrict__ bias,
                  float* __restrict__ out) {
    const int b  = blockIdx.x;
    const int h0 = blockIdx.y * HT;

    __shared__ __align__(16) unsigned short As1[LL][LSTR];  // x1 tile, k-contiguous
    __shared__ __align__(16) unsigned short As2[LL][LSTR];  // x2 tile
    __shared__ __align__(16) unsigned short Bs1[HT][LSTR];  // W[:, :512] tile
    __shared__ __align__(16) unsigned short Bs2[HT][LSTR];  // W[:, 512:] tile
    __shared__ float y1t[LL][YSTR];
    __shared__ float y2t[LL][YSTR];
    __shared__ float partial[8][YSTR];

    const int t      = threadIdx.x;
    const int lane   = t & 63;
    const int wid    = t >> 6;          // 0..3
    const int srcSel = wid >> 1;        // 0: y1 rows, 1: y2 rows
    const int mrow   = (wid & 1) * 32;  // wave's 32-row half
    const int lm     = lane & 15;
    const int quad   = lane >> 4;

    // staging mapping
    const int r   = t >> 2;  const int kq  = t & 3;  // A: row 0..63, 16-float quarter
    const int rw  = t >> 3;  const int kq8 = t & 7;  // W: row 0..31, 8-float eighth

    const float* a1p = x1 + (size_t)(b * LL + r) * FF + kq * 16;
    const float* a2p = x2 + (size_t)(b * LL + r) * FF + kq * 16;
    const float* w1p = W + (size_t)(h0 + rw) * WSTRIDE + kq8 * 8;
    const float* w2p = W + (size_t)(h0 + rw) * WSTRIDE + FF + kq8 * 8;

    float4v acc[2][2];
    #pragma unroll
    for (int i = 0; i < 2; ++i)
        #pragma unroll
        for (int j = 0; j < 2; ++j)
            acc[i][j] = (float4v){0.f, 0.f, 0.f, 0.f};

    // prefetch tile 0
    float4 pa1[4], pa2[4], pb1[2], pb2[2];
    #pragma unroll
    for (int q = 0; q < 4; ++q) {
        pa1[q] = *(const float4*)(a1p + q * 4);
        pa2[q] = *(const float4*)(a2p + q * 4);
    }
    #pragma unroll
    for (int q = 0; q < 2; ++q) {
        pb1[q] = *(const float4*)(w1p + q * 4);
        pb2[q] = *(const float4*)(w2p + q * 4);
    }

    // fragment base pointers (R2-verified layout)
    const unsigned short (*Ap)[LSTR] = srcSel ? As2 : As1;
    const unsigned short (*Bp)[LSTR] = srcSel ? Bs2 : Bs1;
    const unsigned short* aF0 = &Ap[mrow + lm][quad * 8];
    const unsigned short* aF1 = &Ap[mrow + 16 + lm][quad * 8];
    const unsigned short* bF0 = &Bp[lm][quad * 8];
    const unsigned short* bF1 = &Bp[16 + lm][quad * 8];

    for (int kt = 0; kt < FF / BK; ++kt) {
        cvt_store16(pa1, &As1[r][kq * 16]);
        cvt_store16(pa2, &As2[r][kq * 16]);
        cvt_store8(pb1, &Bs1[rw][kq8 * 8]);
        cvt_store8(pb2, &Bs2[rw][kq8 * 8]);
        __syncthreads();

        if (kt + 1 < FF / BK) {
            const int ko = (kt + 1) * BK;
            #pragma unroll
            for (int q = 0; q < 4; ++q) {
                pa1[q] = *(const float4*)(a1p + ko + q * 4);
                pa2[q] = *(const float4*)(a2p + ko + q * 4);
            }
            #pragma unroll
            for (int q = 0; q < 2; ++q) {
                pb1[q] = *(const float4*)(w1p + ko + q * 4);
                pb2[q] = *(const float4*)(w2p + ko + q * 4);
            }
        }

        #pragma unroll
        for (int ks = 0; ks < 2; ++ks) {
            const short8 a0 = *(const short8*)(aF0 + ks * 32);
            const short8 a1 = *(const short8*)(aF1 + ks * 32);
            const short8 b0 = *(const short8*)(bF0 + ks * 32);
            const short8 b1 = *(const short8*)(bF1 + ks * 32);
            acc[0][0] = __builtin_amdgcn_mfma_f32_16x16x32_bf16(a0, b0, acc[0][0], 0, 0, 0);
            acc[0][1] = __builtin_amdgcn_mfma_f32_16x16x32_bf16(a0, b1, acc[0][1], 0, 0, 0);
            acc[1][0] = __builtin_amdgcn_mfma_f32_16x16x32_bf16(a1, b0, acc[1][0], 0, 0, 0);
            acc[1][1] = __builtin_amdgcn_mfma_f32_16x16x32_bf16(a1, b1, acc[1][1], 0, 0, 0);
        }
        __syncthreads();
    }

    // epilogue -> LDS y-tiles; fold bias into y2' (C/D: col=lane&15, row=quad*4+j)
    {
        float (*yt)[YSTR] = srcSel ? y2t : y1t;
        float bv[2];
        bv[0] = srcSel ? bias[h0 + lm] : 0.0f;
        bv[1] = srcSel ? bias[h0 + 16 + lm] : 0.0f;
        #pragma unroll
        for (int im = 0; im < 2; ++im)
            #pragma unroll
            for (int in = 0; in < 2; ++in)
                #pragma unroll
                for (int j = 0; j < 4; ++j)
                    yt[mrow + im * 16 + quad * 4 + j][in * 16 + lm] = acc[im][in][j] + bv[in];
    }
    __syncthreads();

    // masked pair relu-sum: thread = (h, i-chunk of 8)
    const int n1 = s1p[b];
    const int n2 = s2p[b];
    const int h  = t & 31;
    const int ic = t >> 5;

    float r1[8];
    #pragma unroll
    for (int ii = 0; ii < 8; ++ii) {
        const int i = ic * 8 + ii;
        r1[ii] = (i < n1) ? y1t[i][h] : -1e30f;  // invalid i -> relu gives 0
    }

    float ac[8] = {0.f, 0.f, 0.f, 0.f, 0.f, 0.f, 0.f, 0.f};
    int j = 0;
    for (; j + 2 <= n2; j += 2) {
        const float v0 = y2t[j][h];
        const float v1 = y2t[j + 1][h];
        #pragma unroll
        for (int ii = 0; ii < 8; ++ii) {
            ac[ii] += fmaxf(r1[ii] + v0, 0.f);
            ac[ii] += fmaxf(r1[ii] + v1, 0.f);
        }
    }
    if (j < n2) {
        const float v0 = y2t[j][h];
        #pragma unroll
        for (int ii = 0; ii < 8; ++ii)
            ac[ii] += fmaxf(r1[ii] + v0, 0.f);
    }
    partial[ic][h] = ((ac[0] + ac[1]) + (ac[2] + ac[3])) + ((ac[4] + ac[5]) + (ac[6] + ac[7]));
    __syncthreads();

    if (t < 32) {
        float s = 0.f;
        #pragma unroll
        for (int ic2 = 0; ic2 < 8; ++ic2)
            s += partial[ic2][t];
        const float denom = (float)(n1 * n2);
        const float pad = (float)(LL * LL) - denom;
        out[b * HH + h0 + t] = (s + pad * fmaxf(bias[h0 + t], 0.f)) / denom;
    }
}

extern "C" void kernel_launch(void* const* d_in, const int* in_sizes, int n_in,
                              void* d_out, int out_size, void* d_ws, size_t ws_size,
                              hipStream_t stream) {
    const float* x1 = (const float*)d_in[0];
    const int*   s1 = (const int*)d_in[1];
    const float* x2 = (const float*)d_in[2];
    const int*   s2 = (const int*)d_in[3];
    const float* W  = (const float*)d_in[4];
    const float* b  = (const float*)d_in[5];
    float* out = (float*)d_out;

    // single fused dispatch; d_ws unused
    fused_kernel<<<dim3(BB, HH / HT), 256, 0, stream>>>(x1, s1, x2, s2, W, b, out);
}

// Round 4
// 76.557 us; speedup vs baseline: 1.4920x; 1.0244x over previous
//
#include <hip/hip_runtime.h>

// Problem constants: B=32, L1=L2=64, DIM_HID=256, FEAT=512
#define BB 32
#define LL 64
#define HH 256
#define FF 512
#define WSTRIDE 1024   // W is [256, 1024] row-major
#define HT 32          // h-tile per block
#define BK 128         // K-tile (4 iterations over K=512)
#define LSTR 136       // bf16 LDS stride: 272 B rows = 17*16 B (b128-aligned, 2-way-read = free)
#define YSTR 33        // f32 y-tile stride (+1 pad)

#define NX1 (BB * LL * FF)          // 1,048,576 floats
#define NX  (2 * NX1)               // x1+x2
#define NW  (HH * WSTRIDE)          // 262,144 floats
#define NTOT (NX + NW)              // 2,359,296 floats (= 1152*256*8 exactly)

typedef float float4v __attribute__((ext_vector_type(4)));
typedef short short8  __attribute__((ext_vector_type(8)));

// fp32 -> bf16 (RNE), bit-level (R2/R3-verified)
static __device__ __forceinline__ unsigned short f2bf(float x) {
    union { float f; unsigned int u; } v; v.f = x;
    v.u += 0x7FFFu + ((v.u >> 16) & 1u);
    return (unsigned short)(v.u >> 16);
}

// ---------------- Kernel 1: fp32 -> bf16 pre-convert into d_ws ----------------
// d_ws layout: [x1 bf16 | x2 bf16] (NX shorts), then W bf16 (NW shorts).
__global__ __launch_bounds__(256)
void convert_kernel(const float* __restrict__ x1,
                    const float* __restrict__ x2,
                    const float* __restrict__ W,
                    unsigned short* __restrict__ xb,
                    unsigned short* __restrict__ Wb) {
    const int idx = (blockIdx.x * 256 + threadIdx.x) * 8;
    const float* src;
    unsigned short* dst;
    if (idx < NX1)      { src = x1 + idx;          dst = xb + idx; }
    else if (idx < NX)  { src = x2 + (idx - NX1);  dst = xb + idx; }
    else                { src = W  + (idx - NX);   dst = Wb + (idx - NX); }
    const float4 v0 = *(const float4*)src;
    const float4 v1 = *(const float4*)(src + 4);
    const float f[8] = {v0.x, v0.y, v0.z, v0.w, v1.x, v1.y, v1.z, v1.w};
    short8 o;
    #pragma unroll
    for (int e = 0; e < 8; ++e)
        ((unsigned short*)&o)[e] = f2bf(f[e]);
    *(short8*)dst = o;
}

// ---------------- Kernel 2: fused bf16 MFMA GEMM + masked pair relu-sum ----------------
// One block per (batch b, h-tile of 32). y1=x1[b]@W1^T, y2'=x2[b]@W2^T+b into
// LDS, then masked pair relu-sum + padding term -> out[b, h0:h0+32].
__global__ __launch_bounds__(256)
void fused_kernel(const unsigned short* __restrict__ xb,
                  const unsigned short* __restrict__ Wb,
                  const int* __restrict__ s1p,
                  const int* __restrict__ s2p,
                  const float* __restrict__ bias,
                  float* __restrict__ out) {
    const int b  = blockIdx.x;
    const int h0 = blockIdx.y * HT;

    // Phase-1 LDS: As1(17408) As2(17408) Bs1(8704) Bs2(8704) = 52224 B.
    // Phase-2 overlays y1t(8448) y2t(8448) partial(1056) on the As region
    // (safe: last MFMA read is fenced by __syncthreads before epilogue writes).
    __shared__ __align__(16) unsigned char smem[52224];
    unsigned short (*As1)[LSTR] = (unsigned short (*)[LSTR])(smem);
    unsigned short (*As2)[LSTR] = (unsigned short (*)[LSTR])(smem + 17408);
    unsigned short (*Bs1)[LSTR] = (unsigned short (*)[LSTR])(smem + 34816);
    unsigned short (*Bs2)[LSTR] = (unsigned short (*)[LSTR])(smem + 43520);
    float (*y1t)[YSTR]    = (float (*)[YSTR])(smem);
    float (*y2t)[YSTR]    = (float (*)[YSTR])(smem + 8448);
    float (*partial)[YSTR] = (float (*)[YSTR])(smem + 16896);

    const int t      = threadIdx.x;
    const int lane   = t & 63;
    const int wid    = t >> 6;          // 0..3
    const int srcSel = wid >> 1;        // 0: y1, 1: y2
    const int mrow   = (wid & 1) * 32;  // wave's 32-row half
    const int lm     = lane & 15;
    const int quad   = lane >> 4;

    // staging maps
    const int r   = t >> 2;  const int kq  = t & 3;  // A: row 0..63, 32-elem quarter (64 B)
    const int rw  = t >> 3;  const int kq8 = t & 7;  // W: row 0..31, 16-elem eighth (32 B)

    const unsigned short* a1p = xb +        (size_t)(b * LL + r) * FF + kq * 32;
    const unsigned short* a2p = xb + NX1 +  (size_t)(b * LL + r) * FF + kq * 32;
    const unsigned short* w1p = Wb + (size_t)(h0 + rw) * WSTRIDE + kq8 * 16;
    const unsigned short* w2p = Wb + (size_t)(h0 + rw) * WSTRIDE + FF + kq8 * 16;

    float4v acc[2][2];
    #pragma unroll
    for (int i = 0; i < 2; ++i)
        #pragma unroll
        for (int j = 0; j < 2; ++j)
            acc[i][j] = (float4v){0.f, 0.f, 0.f, 0.f};

    // prefetch tile 0
    short8 pa1[4], pa2[4], pw1[2], pw2[2];
    #pragma unroll
    for (int q = 0; q < 4; ++q) {
        pa1[q] = *(const short8*)(a1p + q * 8);
        pa2[q] = *(const short8*)(a2p + q * 8);
    }
    #pragma unroll
    for (int q = 0; q < 2; ++q) {
        pw1[q] = *(const short8*)(w1p + q * 8);
        pw2[q] = *(const short8*)(w2p + q * 8);
    }

    // fragment base pointers (R2-verified layout: lane lm = row, quad*8 = k-offset)
    const unsigned short (*Ap)[LSTR] = srcSel ? As2 : As1;
    const unsigned short (*Bp)[LSTR] = srcSel ? Bs2 : Bs1;
    const unsigned short* aF0 = &Ap[mrow + lm][quad * 8];
    const unsigned short* aF1 = &Ap[mrow + 16 + lm][quad * 8];
    const unsigned short* bF0 = &Bp[lm][quad * 8];
    const unsigned short* bF1 = &Bp[16 + lm][quad * 8];

    for (int kt = 0; kt < FF / BK; ++kt) {
        #pragma unroll
        for (int q = 0; q < 4; ++q) {
            *(short8*)&As1[r][kq * 32 + q * 8] = pa1[q];
            *(short8*)&As2[r][kq * 32 + q * 8] = pa2[q];
        }
        #pragma unroll
        for (int q = 0; q < 2; ++q) {
            *(short8*)&Bs1[rw][kq8 * 16 + q * 8] = pw1[q];
            *(short8*)&Bs2[rw][kq8 * 16 + q * 8] = pw2[q];
        }
        __syncthreads();

        if (kt + 1 < FF / BK) {
            const int ko = (kt + 1) * BK;
            #pragma unroll
            for (int q = 0; q < 4; ++q) {
                pa1[q] = *(const short8*)(a1p + ko + q * 8);
                pa2[q] = *(const short8*)(a2p + ko + q * 8);
            }
            #pragma unroll
            for (int q = 0; q < 2; ++q) {
                pw1[q] = *(const short8*)(w1p + ko + q * 8);
                pw2[q] = *(const short8*)(w2p + ko + q * 8);
            }
        }

        #pragma unroll
        for (int ks = 0; ks < 4; ++ks) {
            const short8 a0 = *(const short8*)(aF0 + ks * 32);
            const short8 a1 = *(const short8*)(aF1 + ks * 32);
            const short8 b0 = *(const short8*)(bF0 + ks * 32);
            const short8 b1 = *(const short8*)(bF1 + ks * 32);
            acc[0][0] = __builtin_amdgcn_mfma_f32_16x16x32_bf16(a0, b0, acc[0][0], 0, 0, 0);
            acc[0][1] = __builtin_amdgcn_mfma_f32_16x16x32_bf16(a0, b1, acc[0][1], 0, 0, 0);
            acc[1][0] = __builtin_amdgcn_mfma_f32_16x16x32_bf16(a1, b0, acc[1][0], 0, 0, 0);
            acc[1][1] = __builtin_amdgcn_mfma_f32_16x16x32_bf16(a1, b1, acc[1][1], 0, 0, 0);
        }
        __syncthreads();
    }

    // epilogue -> LDS y-tiles (overlay); fold bias into y2'
    // C/D layout: col = lane&15, row = quad*4 + j (m89-verified)
    {
        float (*yt)[YSTR] = srcSel ? y2t : y1t;
        float bv[2];
        bv[0] = srcSel ? bias[h0 + lm] : 0.0f;
        bv[1] = srcSel ? bias[h0 + 16 + lm] : 0.0f;
        #pragma unroll
        for (int im = 0; im < 2; ++im)
            #pragma unroll
            for (int in = 0; in < 2; ++in)
                #pragma unroll
                for (int j = 0; j < 4; ++j)
                    yt[mrow + im * 16 + quad * 4 + j][in * 16 + lm] = acc[im][in][j] + bv[in];
    }
    __syncthreads();

    // masked pair relu-sum: thread = (h in 0..31, i-chunk of 8)
    const int n1 = s1p[b];
    const int n2 = s2p[b];
    const int h  = t & 31;
    const int ic = t >> 5;

    float r1[8];
    #pragma unroll
    for (int ii = 0; ii < 8; ++ii) {
        const int i = ic * 8 + ii;
        r1[ii] = (i < n1) ? y1t[i][h] : -1e30f;  // invalid i -> relu gives 0
    }

    float ac[8] = {0.f, 0.f, 0.f, 0.f, 0.f, 0.f, 0.f, 0.f};
    int j = 0;
    for (; j + 2 <= n2; j += 2) {
        const float v0 = y2t[j][h];
        const float v1 = y2t[j + 1][h];
        #pragma unroll
        for (int ii = 0; ii < 8; ++ii) {
            ac[ii] += fmaxf(r1[ii] + v0, 0.f);
            ac[ii] += fmaxf(r1[ii] + v1, 0.f);
        }
    }
    if (j < n2) {
        const float v0 = y2t[j][h];
        #pragma unroll
        for (int ii = 0; ii < 8; ++ii)
            ac[ii] += fmaxf(r1[ii] + v0, 0.f);
    }
    partial[ic][h] = ((ac[0] + ac[1]) + (ac[2] + ac[3])) + ((ac[4] + ac[5]) + (ac[6] + ac[7]));
    __syncthreads();

    if (t < 32) {
        float s = 0.f;
        #pragma unroll
        for (int ic2 = 0; ic2 < 8; ++ic2)
            s += partial[ic2][t];
        const float denom = (float)(n1 * n2);
        const float pad = (float)(LL * LL) - denom;
        out[b * HH + h0 + t] = (s + pad * fmaxf(bias[h0 + t], 0.f)) / denom;
    }
}

extern "C" void kernel_launch(void* const* d_in, const int* in_sizes, int n_in,
                              void* d_out, int out_size, void* d_ws, size_t ws_size,
                              hipStream_t stream) {
    const float* x1 = (const float*)d_in[0];
    const int*   s1 = (const int*)d_in[1];
    const float* x2 = (const float*)d_in[2];
    const int*   s2 = (const int*)d_in[3];
    const float* W  = (const float*)d_in[4];
    const float* b  = (const float*)d_in[5];
    float* out = (float*)d_out;

    unsigned short* xb = (unsigned short*)d_ws;      // x1,x2 bf16 (NX shorts)
    unsigned short* Wb = xb + NX;                    // W bf16 (NW shorts)

    convert_kernel<<<NTOT / (256 * 8), 256, 0, stream>>>(x1, x2, W, xb, Wb);
    fused_kernel<<<dim3(BB, HH / HT), 256, 0, stream>>>(xb, Wb, s1, s2, b, out);
}

// Round 5
// 76.362 us; speedup vs baseline: 1.4958x; 1.0026x over previous
//
#include <hip/hip_runtime.h>

// Problem constants: B=32, L1=L2=64, DIM_HID=256, FEAT=512
#define BB 32
#define LL 64
#define HH 256
#define FF 512
#define WSTRIDE 1024   // W is [256, 1024] row-major
#define HT 16          // h-tile per block (R5: halved -> 512 blocks = 2/CU)
#define BK 128         // K-tile (4 iterations over K=512)
#define LSTR 136       // bf16 LDS stride: 272 B rows = 17*16 B (b128-aligned)
#define YSTR 17        // f32 y-tile stride (16 + 1 pad)

#define NX1 (BB * LL * FF)          // 1,048,576 floats
#define NX  (2 * NX1)               // x1+x2
#define NW  (HH * WSTRIDE)          // 262,144 floats
#define NTOT (NX + NW)              // 2,359,296 floats

typedef float float4v __attribute__((ext_vector_type(4)));
typedef short short8  __attribute__((ext_vector_type(8)));

// fp32 -> bf16 (RNE), bit-level (R2-R4-verified)
static __device__ __forceinline__ unsigned short f2bf(float x) {
    union { float f; unsigned int u; } v; v.f = x;
    v.u += 0x7FFFu + ((v.u >> 16) & 1u);
    return (unsigned short)(v.u >> 16);
}

// ---------------- Kernel 1: fp32 -> bf16 pre-convert into d_ws ----------------
__global__ __launch_bounds__(256)
void convert_kernel(const float* __restrict__ x1,
                    const float* __restrict__ x2,
                    const float* __restrict__ W,
                    unsigned short* __restrict__ xb,
                    unsigned short* __restrict__ Wb) {
    const int idx = (blockIdx.x * 256 + threadIdx.x) * 8;
    const float* src;
    unsigned short* dst;
    if (idx < NX1)      { src = x1 + idx;          dst = xb + idx; }
    else if (idx < NX)  { src = x2 + (idx - NX1);  dst = xb + idx; }
    else                { src = W  + (idx - NX);   dst = Wb + (idx - NX); }
    const float4 v0 = *(const float4*)src;
    const float4 v1 = *(const float4*)(src + 4);
    const float f[8] = {v0.x, v0.y, v0.z, v0.w, v1.x, v1.y, v1.z, v1.w};
    short8 o;
    #pragma unroll
    for (int e = 0; e < 8; ++e)
        ((unsigned short*)&o)[e] = f2bf(f[e]);
    *(short8*)dst = o;
}

// ---------------- Kernel 2: fused bf16 MFMA GEMM + masked pair relu-sum ----------------
// One block per (batch b, h-tile of 16). 512 blocks = 2/CU for latency hiding.
// Waves: srcSel=wid>>1 picks y1/y2; each wave computes 32 rows x 16 cols.
__global__ __launch_bounds__(256)
void fused_kernel(const unsigned short* __restrict__ xb,
                  const unsigned short* __restrict__ Wb,
                  const int* __restrict__ s1p,
                  const int* __restrict__ s2p,
                  const float* __restrict__ bias,
                  float* __restrict__ out) {
    const int b  = blockIdx.x;
    const int h0 = blockIdx.y * HT;

    // Phase-1 LDS: As1(17408) As2(17408) Bs1(4352) Bs2(4352) = 43520 B.
    // Phase-2 overlays y1t(4352) y2t(4352) partial(1088) on the As1 region
    // (fenced by __syncthreads after the last MFMA fragment read).
    __shared__ __align__(16) unsigned char smem[43520];
    unsigned short (*As1)[LSTR] = (unsigned short (*)[LSTR])(smem);
    unsigned short (*As2)[LSTR] = (unsigned short (*)[LSTR])(smem + 17408);
    unsigned short (*Bs1)[LSTR] = (unsigned short (*)[LSTR])(smem + 34816);
    unsigned short (*Bs2)[LSTR] = (unsigned short (*)[LSTR])(smem + 39168);
    float (*y1t)[YSTR]     = (float (*)[YSTR])(smem);
    float (*y2t)[YSTR]     = (float (*)[YSTR])(smem + 4352);
    float (*partial)[YSTR] = (float (*)[YSTR])(smem + 8704);

    const int t      = threadIdx.x;
    const int lane   = t & 63;
    const int wid    = t >> 6;          // 0..3
    const int srcSel = wid >> 1;        // 0: y1, 1: y2
    const int mrow   = (wid & 1) * 32;  // wave's 32-row half
    const int lm     = lane & 15;
    const int quad   = lane >> 4;

    // staging maps
    const int r    = t >> 2;  const int kq   = t & 3;   // A: row 0..63, 32-short quarter
    const int rw   = t >> 4;  const int kq16 = t & 15;  // W: row 0..15, 8-short sixteenth

    const unsigned short* a1p = xb +       (size_t)(b * LL + r) * FF + kq * 32;
    const unsigned short* a2p = xb + NX1 + (size_t)(b * LL + r) * FF + kq * 32;
    const unsigned short* w1p = Wb + (size_t)(h0 + rw) * WSTRIDE + kq16 * 8;
    const unsigned short* w2p = Wb + (size_t)(h0 + rw) * WSTRIDE + FF + kq16 * 8;

    float4v acc[2];
    acc[0] = (float4v){0.f, 0.f, 0.f, 0.f};
    acc[1] = (float4v){0.f, 0.f, 0.f, 0.f};

    // prefetch tile 0
    short8 pa1[4], pa2[4], pw1, pw2;
    #pragma unroll
    for (int q = 0; q < 4; ++q) {
        pa1[q] = *(const short8*)(a1p + q * 8);
        pa2[q] = *(const short8*)(a2p + q * 8);
    }
    pw1 = *(const short8*)w1p;
    pw2 = *(const short8*)w2p;

    // fragment base pointers (R2-verified layout: lane lm = row, quad*8 = k-offset)
    const unsigned short (*Ap)[LSTR] = srcSel ? As2 : As1;
    const unsigned short (*Bp)[LSTR] = srcSel ? Bs2 : Bs1;
    const unsigned short* aF0 = &Ap[mrow + lm][quad * 8];
    const unsigned short* aF1 = &Ap[mrow + 16 + lm][quad * 8];
    const unsigned short* bF0 = &Bp[lm][quad * 8];

    for (int kt = 0; kt < FF / BK; ++kt) {
        #pragma unroll
        for (int q = 0; q < 4; ++q) {
            *(short8*)&As1[r][kq * 32 + q * 8] = pa1[q];
            *(short8*)&As2[r][kq * 32 + q * 8] = pa2[q];
        }
        *(short8*)&Bs1[rw][kq16 * 8] = pw1;
        *(short8*)&Bs2[rw][kq16 * 8] = pw2;
        __syncthreads();

        if (kt + 1 < FF / BK) {
            const int ko = (kt + 1) * BK;
            #pragma unroll
            for (int q = 0; q < 4; ++q) {
                pa1[q] = *(const short8*)(a1p + ko + q * 8);
                pa2[q] = *(const short8*)(a2p + ko + q * 8);
            }
            pw1 = *(const short8*)(w1p + ko);
            pw2 = *(const short8*)(w2p + ko);
        }

        #pragma unroll
        for (int ks = 0; ks < 4; ++ks) {
            const short8 a0 = *(const short8*)(aF0 + ks * 32);
            const short8 a1 = *(const short8*)(aF1 + ks * 32);
            const short8 b0 = *(const short8*)(bF0 + ks * 32);
            acc[0] = __builtin_amdgcn_mfma_f32_16x16x32_bf16(a0, b0, acc[0], 0, 0, 0);
            acc[1] = __builtin_amdgcn_mfma_f32_16x16x32_bf16(a1, b0, acc[1], 0, 0, 0);
        }
        __syncthreads();
    }

    // epilogue -> LDS y-tiles (overlay); fold bias into y2'
    // C/D layout: col = lane&15, row = quad*4 + j (m89-verified)
    {
        float (*yt)[YSTR] = srcSel ? y2t : y1t;
        const float bv = srcSel ? bias[h0 + lm] : 0.0f;
        #pragma unroll
        for (int im = 0; im < 2; ++im)
            #pragma unroll
            for (int j = 0; j < 4; ++j)
                yt[mrow + im * 16 + quad * 4 + j][lm] = acc[im][j] + bv;
    }
    __syncthreads();

    // masked pair relu-sum: thread = (h in 0..15, i-chunk of 4)
    const int n1 = s1p[b];
    const int n2 = s2p[b];
    const int h  = t & 15;
    const int ic = t >> 4;   // 0..15

    float r1[4];
    #pragma unroll
    for (int ii = 0; ii < 4; ++ii) {
        const int i = ic * 4 + ii;
        r1[ii] = (i < n1) ? y1t[i][h] : -1e30f;  // invalid i -> relu gives 0
    }

    float ac[4] = {0.f, 0.f, 0.f, 0.f};
    int j = 0;
    for (; j + 4 <= n2; j += 4) {
        const float v0 = y2t[j][h];
        const float v1 = y2t[j + 1][h];
        const float v2 = y2t[j + 2][h];
        const float v3 = y2t[j + 3][h];
        #pragma unroll
        for (int ii = 0; ii < 4; ++ii) {
            ac[ii] += fmaxf(r1[ii] + v0, 0.f);
            ac[ii] += fmaxf(r1[ii] + v1, 0.f);
            ac[ii] += fmaxf(r1[ii] + v2, 0.f);
            ac[ii] += fmaxf(r1[ii] + v3, 0.f);
        }
    }
    for (; j < n2; ++j) {
        const float v0 = y2t[j][h];
        #pragma unroll
        for (int ii = 0; ii < 4; ++ii)
            ac[ii] += fmaxf(r1[ii] + v0, 0.f);
    }
    partial[ic][h] = (ac[0] + ac[1]) + (ac[2] + ac[3]);
    __syncthreads();

    if (t < HT) {
        float s = 0.f;
        #pragma unroll
        for (int ic2 = 0; ic2 < 16; ++ic2)
            s += partial[ic2][t];
        const float denom = (float)(n1 * n2);
        const float pad = (float)(LL * LL) - denom;
        out[b * HH + h0 + t] = (s + pad * fmaxf(bias[h0 + t], 0.f)) / denom;
    }
}

extern "C" void kernel_launch(void* const* d_in, const int* in_sizes, int n_in,
                              void* d_out, int out_size, void* d_ws, size_t ws_size,
                              hipStream_t stream) {
    const float* x1 = (const float*)d_in[0];
    const int*   s1 = (const int*)d_in[1];
    const float* x2 = (const float*)d_in[2];
    const int*   s2 = (const int*)d_in[3];
    const float* W  = (const float*)d_in[4];
    const float* b  = (const float*)d_in[5];
    float* out = (float*)d_out;

    unsigned short* xb = (unsigned short*)d_ws;   // x1,x2 bf16 (NX shorts)
    unsigned short* Wb = xb + NX;                 // W bf16 (NW shorts)

    convert_kernel<<<NTOT / (256 * 8), 256, 0, stream>>>(x1, x2, W, xb, Wb);
    fused_kernel<<<dim3(BB, HH / HT), 256, 0, stream>>>(xb, Wb, s1, s2, b, out);
}